// Round 14
// baseline (672.639 us; speedup 1.0000x reference)
//
#include <hip/hip_runtime.h>
#include <math.h>

#define NRAYS 16384
#define NC    64
#define NF    128
#define NZ    192   // NC + NF
#define H     64

typedef __attribute__((ext_vector_type(8))) short bf16x8;  // 8 bf16 (4 VGPRs)
typedef __attribute__((ext_vector_type(4))) float f32x4;   // MFMA C/D
typedef __attribute__((ext_vector_type(4))) int   i32x4;

__device__ __forceinline__ float wave_incl_scan(float v, int lane) {
#pragma unroll
  for (int off = 1; off < 64; off <<= 1) {
    float n = __shfl_up(v, off);
    v = (lane >= off) ? v + n : v;
  }
  return v;
}

__device__ __forceinline__ float wave_incl_max_scan(float v, int lane) {
#pragma unroll
  for (int off = 1; off < 64; off <<= 1) {
    float n = __shfl_up(v, off);
    v = (lane >= off) ? fmaxf(v, n) : v;
  }
  return v;
}

__device__ __forceinline__ float wave_sum(float v) {
#pragma unroll
  for (int off = 32; off > 0; off >>= 1) v += __shfl_xor(v, off);
  return v;
}

// fp32 -> bf16 hi + bf16 lo (truncation split; 3-term MFMA has rel err ~2^-15).
// R13's 2-term variant failed with an all-zeros signature that numerics cannot
// explain -- reverted to this KNOWN-GOOD (R12) 3-term path.
__device__ __forceinline__ void split_bf16(float f, short& hi, short& lo) {
  unsigned u = __float_as_uint(f);
  hi = (short)(u >> 16);
  float rem = f - __uint_as_float(u & 0xFFFF0000u);   // exact
  lo = (short)(__float_as_uint(rem) >> 16);
}

__device__ __forceinline__ float sigmoidf(float x) {
  return 1.f / (1.f + expf(-x));
}

// Layer-1 weights in LDS — read 16x per ray (a/b precompute).
struct __align__(16) WLds {
  float W1b[H][4];   // {w1[0][k], w1[1][k], w1[2][k], b1[k]}
};

// h1_k = relu(a_k + z*b_k); a,b per-ray constants in registers (R11 win).
struct RayAB { float a[16]; float b[16]; };   // idx = kt*8 + j

__device__ __forceinline__ void compute_ray_ab(
    int lane, float ox, float oy, float oz, float dx, float dy, float dz,
    const WLds& W, RayAB& AB)
{
  const int quad = lane >> 4;
#pragma unroll
  for (int kt = 0; kt < 2; ++kt) {
#pragma unroll
    for (int j = 0; j < 8; ++j) {
      const int k = kt*32 + quad*8 + j;
      const float4 wv = *(const float4*)(&W.W1b[k][0]);
      AB.a[kt*8+j] = fmaf(ox, wv.x, fmaf(oy, wv.y, fmaf(oz, wv.z, wv.w)));
      AB.b[kt*8+j] = fmaf(dx, wv.x, fmaf(dy, wv.y, dz * wv.z));
    }
  }
}

// Register-resident w2 fragments (3-term split, R12 numerics).
// 16x16x32 bf16 layouts (HW-verified, guide §3).
struct MfmaW {
  bf16x8 Bhi[2][4], Blo[2][4];  // w2 [kt][jt]
  float  hbown;                 // head bias for this lane's c = n16&3
};

__device__ __forceinline__ void load_mfma_weights(
    int lane,
    const float* __restrict__ w2,
    const float* __restrict__ br, const float* __restrict__ bd,
    MfmaW& M)
{
  const int quad = lane >> 4, n16 = lane & 15;
#pragma unroll
  for (int kt = 0; kt < 2; ++kt) {
#pragma unroll
    for (int jt = 0; jt < 4; ++jt) {
#pragma unroll
      for (int j = 0; j < 8; ++j) {
        const int k = kt*32 + quad*8 + j;
        short hi, lo;
        split_bf16(w2[k*H + jt*16 + n16], hi, lo);
        M.Bhi[kt][jt][j] = hi; M.Blo[kt][jt][j] = lo;
      }
    }
  }
  const int c = n16 & 3;
  M.hbown = (c == 0) ? br[0] : (c == 1) ? br[1] : (c == 2) ? br[2] : bd[0];
}

// One 64-sample MLP batch. Layer1: regs. Layer2: 3-term split-bf16 MFMA.
// Head: in-lane fp32 (LDS weights) + halving butterfly, with stage 1 fused
// into the P-production loop (R14: live set P[16] -> Q[8]+4 temps).
// Output R[sample*4 + c], bias included.
__device__ __forceinline__ void mlp_mfma_batch(
    int lane, const RayAB& AB,
    const float* __restrict__ zsrc, const MfmaW& M,
    const float (*__restrict__ sHW)[4], const float* __restrict__ sB2,
    float* __restrict__ R)
{
  const int quad = lane >> 4, n16 = lane & 15;
  float b2q[4];
#pragma unroll
  for (int jt = 0; jt < 4; ++jt) b2q[jt] = sB2[jt*16 + n16];
#pragma unroll 1   // rolled: prevents register blow-up (R5/R6 lesson)
  for (int mt = 0; mt < 4; ++mt) {
    const float z = zsrc[mt*16 + n16];
    f32x4 C[4];
#pragma unroll
    for (int jt = 0; jt < 4; ++jt)
      C[jt] = (f32x4){b2q[jt], b2q[jt], b2q[jt], b2q[jt]};
#pragma unroll
    for (int kt = 0; kt < 2; ++kt) {
      // h1 with truncation hi/lo split (pair-packed, 3 int ops per word)
      i32x4 hip, lop;
#pragma unroll
      for (int j2 = 0; j2 < 4; ++j2) {
        const float h0 = fmaxf(fmaf(z, AB.b[kt*8+2*j2],   AB.a[kt*8+2*j2]),   0.f);
        const float h1 = fmaxf(fmaf(z, AB.b[kt*8+2*j2+1], AB.a[kt*8+2*j2+1]), 0.f);
        const unsigned u0 = __float_as_uint(h0), u1 = __float_as_uint(h1);
        hip[j2] = (int)((u0 >> 16) | (u1 & 0xFFFF0000u));
        const float r0 = h0 - __uint_as_float(u0 & 0xFFFF0000u);
        const float r1 = h1 - __uint_as_float(u1 & 0xFFFF0000u);
        lop[j2] = (int)((__float_as_uint(r0) >> 16) |
                        (__float_as_uint(r1) & 0xFFFF0000u));
      }
      union { i32x4 i; bf16x8 h; } uh, ul;
      uh.i = hip; ul.i = lop;
#pragma unroll
      for (int jt = 0; jt < 4; ++jt) {
        C[jt] = __builtin_amdgcn_mfma_f32_16x16x32_bf16(uh.h, M.Bhi[kt][jt], C[jt], 0, 0, 0);
        C[jt] = __builtin_amdgcn_mfma_f32_16x16x32_bf16(ul.h, M.Bhi[kt][jt], C[jt], 0, 0, 0);
        C[jt] = __builtin_amdgcn_mfma_f32_16x16x32_bf16(uh.h, M.Blo[kt][jt], C[jt], 0, 0, 0);
      }
    }
    // ---- head: P[r*4+c] = sum_jt relu(C[jt][r]) * sHW[jt*16+n16][c],
    // butterfly stage 1 (xor 1) fused per-r. Mapping preserved from R12:
    // Q[2r]   = pair(P[4r+0], P[4r+1]),  Q[2r+1] = pair(P[4r+2], P[4r+3]).
    float4 hw[4];
#pragma unroll
    for (int jt = 0; jt < 4; ++jt)
      hw[jt] = *(const float4*)(&sHW[jt*16 + n16][0]);
    const bool b0 = (n16 & 1), b1 = (n16 & 2), b2_ = (n16 & 4), b3 = (n16 & 8);
    float Q[8];
#pragma unroll
    for (int r = 0; r < 4; ++r) {
      float p0 = 0.f, p1 = 0.f, p2 = 0.f, p3 = 0.f;
#pragma unroll
      for (int jt = 0; jt < 4; ++jt) {
        const float h2v = fmaxf(C[jt][r], 0.f);
        p0 = fmaf(h2v, hw[jt].x, p0);
        p1 = fmaf(h2v, hw[jt].y, p1);
        p2 = fmaf(h2v, hw[jt].z, p2);
        p3 = fmaf(h2v, hw[jt].w, p3);
      }
      {
        const float give = b0 ? p0 : p1;
        const float keep = b0 ? p1 : p0;
        Q[r*2 + 0] = keep + __shfl_xor(give, 1);
      }
      {
        const float give = b0 ? p2 : p3;
        const float keep = b0 ? p3 : p2;
        Q[r*2 + 1] = keep + __shfl_xor(give, 1);
      }
    }
    float U[4];
#pragma unroll
    for (int t = 0; t < 4; ++t) {
      const float give = b1 ? Q[2*t] : Q[2*t+1];
      const float keep = b1 ? Q[2*t+1] : Q[2*t];
      U[t] = keep + __shfl_xor(give, 2);
    }
    float V[2];
#pragma unroll
    for (int u = 0; u < 2; ++u) {
      const float give = b2_ ? U[2*u] : U[2*u+1];
      const float keep = b2_ ? U[2*u+1] : U[2*u];
      V[u] = keep + __shfl_xor(give, 4);
    }
    {
      const float give = b3 ? V[0] : V[1];
      const float keep = b3 ? V[1] : V[0];
      const float total = keep + __shfl_xor(give, 8);
      R[mt*64 + lane] = total + M.hbown;   // coalesced: addr = sample*4 + c
    }
  }
  __builtin_amdgcn_wave_barrier();     // R complete before readback
}

// Coarse pass for one ray, ONE wave, wave-private LDS scratch.
__device__ __forceinline__ void coarse_pass(
    int ray, int lane,
    const float* __restrict__ origins, const float* __restrict__ dirs,
    const float* __restrict__ nearp, const float* __restrict__ farp,
    const float* __restrict__ bkgd,
    const WLds& W, const MfmaW& M,
    const float (*__restrict__ sHW)[4], const float* __restrict__ sB2,
    float* __restrict__ R,
    float* __restrict__ sT, float* __restrict__ sBins,
    float* __restrict__ sCdf, float* __restrict__ sZs,
    float* __restrict__ zdst, bool emit, float* __restrict__ out)
{
  const float nearv = nearp[ray];
  const float farv  = farp[ray];
  const float ox = origins[ray*3+0], oy = origins[ray*3+1], oz = origins[ray*3+2];
  const float dx = dirs[ray*3+0],    dy = dirs[ray*3+1],    dz = dirs[ray*3+2];

  RayAB AB;
  compute_ray_ab(lane, ox, oy, oz, dx, dy, dz, W, AB);

  const float u_i  = (float)lane / 63.0f;
  const float u_n  = (float)(lane + 1) / 63.0f;
  const float tv    = nearv * (1.f - u_i) + farv * u_i;
  const float tnext = nearv * (1.f - u_n) + farv * u_n;

  sT[lane] = tv;
  if (lane < NC-1) sBins[lane] = 0.5f * (tv + tnext);
  zdst[lane] = 0.f; zdst[lane+64] = 0.f; zdst[lane+128] = 0.f;
  __builtin_amdgcn_wave_barrier();     // sT ready for the batch

  mlp_mfma_batch(lane, AB, sT, M, sHW, sB2, R);
  const float4 rr = *(const float4*)(&R[lane*4]);
  const float rgb0 = sigmoidf(rr.x), rgb1 = sigmoidf(rr.y), rgb2 = sigmoidf(rr.z);
  const float dens = fmaxf(rr.w, 0.f);

  const float dnorm = sqrtf(dx*dx + dy*dy + dz*dz);
  const float tdist = (lane == NC-1) ? 1e10f : (tnext - tv);
  const float dd    = fminf(dens * (tdist * dnorm), 1e4f);
  const float incl  = wave_incl_scan(dd, lane);
  const float excl  = incl - dd;
  const float alpha = 1.f - expf(-dd);
  const float trans = expf(-excl);
  const float w     = alpha * trans;

  if (emit) {
    const float near0 = nearp[0], far0 = farp[0];
    const float t0v   = near0 * (1.f - u_i) + far0 * u_i;
    const float s_w   = wave_sum(w);
    const float s_wt  = wave_sum(w * tv);
    const float s_c0  = wave_sum(w * rgb0);
    const float s_c1  = wave_sum(w * rgb1);
    const float s_c2  = wave_sum(w * rgb2);
    const float s_wt0 = wave_sum(w * t0v);
    if (lane == 0) {
      const float bk0 = bkgd[0], bk1 = bkgd[1], bk2 = bkgd[2];
      const float o0x = origins[0], o0y = origins[1], o0z = origins[2];
      const float d0x = dirs[0],    d0y = dirs[1],    d0z = dirs[2];
      const float oma = 1.f - s_w;
      float* o = out + (size_t)ray * 16;
      o[0] = s_c0 + bk0 * oma;
      o[1] = s_c1 + bk1 * oma;
      o[2] = s_c2 + bk2 * oma;
      o[3] = s_wt;
      o[4] = s_w;
      o[5] = s_w * o0x + s_wt0 * d0x;
      o[6] = s_w * o0y + s_wt0 * d0y;
      o[7] = s_w * o0z + s_wt0 * d0z;
    }
  }

  // ---- PDF -> CDF (62 weights = w[1..62]) ----
  const float wnext = __shfl_down(w, 1);
  const float pw = (lane < NC-2) ? wnext : 0.f;
  const float ws_sum = wave_sum(pw);
  const float pad = fmaxf(1e-5f - ws_sum, 0.f);
  const float wsp = ws_sum + pad;
  const float pdf = (lane < NC-2) ? (pw + pad * (1.f/62.f)) / wsp : 0.f;
  float ip  = wave_incl_scan(pdf, lane);
  ip = wave_incl_max_scan(ip, lane);       // exact monotone
  if (lane < 61)  sCdf[lane+1] = fminf(ip, 1.f);
  if (lane == 61) sCdf[0]  = 0.f;
  if (lane == 62) sCdf[62] = 1.f;
  __builtin_amdgcn_wave_barrier();

  // ---- inverse-CDF: 128 samples, 2 per lane ----
  const float ustep = (1.0f - 1.1920929e-07f) / 127.0f;
#pragma unroll
  for (int r = 0; r < 2; ++r) {
    const int k = lane + 64*r;
    const float u = k * ustep;
    int lo = 0, hi = 61;
    while (lo < hi) {
      const int mid = (lo + hi + 1) >> 1;
      if (sCdf[mid] <= u) lo = mid; else hi = mid - 1;
    }
    const int J = lo;
    const float cg0 = sCdf[J],  cg1 = sCdf[J+1];
    const float bg0 = sBins[J], bg1 = sBins[J+1];
    const float denom = cg1 - cg0;
    const float num   = u - cg0;
    float tt;
    if (denom > 0.f) tt = fminf(fmaxf(num / denom, 0.f), 1.f);
    else             tt = (num > 0.f) ? 1.f : 0.f;
    sZs[k] = fmaf(tt, bg1 - bg0, bg0);
  }
  __builtin_amdgcn_wave_barrier();

  // ---- stable rank merge of sorted t (64) and z (128) into zdst (192) ----
  {
    int l = 0, r = NF;
    while (l < r) { const int m = (l + r) >> 1; if (sZs[m] < tv) l = m + 1; else r = m; }
    zdst[lane + l] = tv;
  }
#pragma unroll
  for (int r2 = 0; r2 < 2; ++r2) {
    const int k = lane + 64*r2;
    const float z = sZs[k];
    int l = 0, r = NC;
    while (l < r) { const int m = (l + r) >> 1; if (sT[m] <= z) l = m + 1; else r = m; }
    zdst[k + l] = z;
  }
  __builtin_amdgcn_wave_barrier();
}

// -------- Kernel 1: ONE block, ONE wave — ray 0's merged z row -> d_ws ------
__global__ __launch_bounds__(64) void nerf_z0_kernel(
    const float* __restrict__ origins, const float* __restrict__ dirs,
    const float* __restrict__ nearp, const float* __restrict__ farp,
    const float* __restrict__ w1c, const float* __restrict__ b1c,
    const float* __restrict__ w2c, const float* __restrict__ b2c,
    const float* __restrict__ wrc, const float* __restrict__ brc,
    const float* __restrict__ wdc, const float* __restrict__ bdc,
    float* __restrict__ gz0)
{
  __shared__ WLds sW;
  __shared__ float sHW[H][4];
  __shared__ float sB2[H];
  __shared__ float sT[NC], sBins[NC], sCdf[NC], sZs[NF], sZv0[NZ];
  __shared__ float sR[256];

  const int lane = threadIdx.x;
  {
    const int k = lane;
    sW.W1b[k][0] = w1c[0*H + k];
    sW.W1b[k][1] = w1c[1*H + k];
    sW.W1b[k][2] = w1c[2*H + k];
    sW.W1b[k][3] = b1c[k];
    sHW[k][0] = wrc[k*3 + 0];
    sHW[k][1] = wrc[k*3 + 1];
    sHW[k][2] = wrc[k*3 + 2];
    sHW[k][3] = wdc[k];
    sB2[k]    = b2c[k];
  }
  __syncthreads();

  MfmaW Mc;
  load_mfma_weights(lane, w2c, brc, bdc, Mc);

  coarse_pass(0, lane, origins, dirs, nearp, farp, /*bkgd*/nullptr,
              sW, Mc, sHW, sB2, sR, sT, sBins, sCdf, sZs, sZv0,
              /*emit=*/false, /*out=*/nullptr);

#pragma unroll
  for (int s = 0; s < 3; ++s) gz0[lane + 64*s] = sZv0[lane + 64*s];
}

// -------- Kernel 2: 4 waves = 4 rays per block; z0 row read from d_ws -------
// __launch_bounds__(256,4): request 4 waves/SIMD (cap 128 VGPR; R12 was 136).
// Spill alarm = WRITE_SIZE (output-only is ~1024 KB).
__global__ __launch_bounds__(256, 4) void nerf_fused_kernel(
    const float* __restrict__ origins, const float* __restrict__ dirs,
    const float* __restrict__ nearp, const float* __restrict__ farp,
    const float* __restrict__ bkgd,
    const float* __restrict__ w1c, const float* __restrict__ b1c,
    const float* __restrict__ w2c, const float* __restrict__ b2c,
    const float* __restrict__ wrc, const float* __restrict__ brc,
    const float* __restrict__ wdc, const float* __restrict__ bdc,
    const float* __restrict__ w1f, const float* __restrict__ b1f,
    const float* __restrict__ w2f, const float* __restrict__ b2f_,
    const float* __restrict__ wrf, const float* __restrict__ brf,
    const float* __restrict__ wdf, const float* __restrict__ bdf,
    const float* __restrict__ gz0, float* __restrict__ out)
{
  __shared__ WLds sWc, sWf;
  __shared__ float sHWc[H][4], sHWf[H][4];
  __shared__ float sB2c[H], sB2f[H];
  __shared__ float sT[4][NC];
  __shared__ float sBins[4][NC];
  __shared__ float sCdf[4][NC];
  __shared__ float sZs[4][NF];
  __shared__ float sZv[4][NZ];
  __shared__ float sZv0[NZ];                // ray 0's fine z row (quirk)
  __shared__ float sR[4][3*256];            // per-wave logits, 3 fine buffers

  const int tid  = threadIdx.x;
  const int wv   = tid >> 6;
  const int lane = tid & 63;
  const int ray  = blockIdx.x * 4 + wv;

  if (tid < 64) {
    const int k = tid;
    sWc.W1b[k][0] = w1c[0*H + k];
    sWc.W1b[k][1] = w1c[1*H + k];
    sWc.W1b[k][2] = w1c[2*H + k];
    sWc.W1b[k][3] = b1c[k];
    sHWc[k][0] = wrc[k*3+0]; sHWc[k][1] = wrc[k*3+1];
    sHWc[k][2] = wrc[k*3+2]; sHWc[k][3] = wdc[k];
    sB2c[k] = b2c[k];
  } else if (tid < 128) {
    const int k = tid - 64;
    sWf.W1b[k][0] = w1f[0*H + k];
    sWf.W1b[k][1] = w1f[1*H + k];
    sWf.W1b[k][2] = w1f[2*H + k];
    sWf.W1b[k][3] = b1f[k];
    sHWf[k][0] = wrf[k*3+0]; sHWf[k][1] = wrf[k*3+1];
    sHWf[k][2] = wrf[k*3+2]; sHWf[k][3] = wdf[k];
    sB2f[k] = b2f_[k];
  }
  if (tid < NZ) sZv0[tid] = gz0[tid];       // z0 row from kernel 1
  __syncthreads();

  float* R = sR[wv];

  // ---- coarse pass (own ray only — no per-block ray-0 recompute) ----
  {
    MfmaW Mc;
    load_mfma_weights(lane, w2c, brc, bdc, Mc);
    coarse_pass(ray, lane, origins, dirs, nearp, farp, bkgd,
                sWc, Mc, sHWc, sB2c, R,
                sT[wv], sBins[wv], sCdf[wv], sZs[wv], sZv[wv], true, out);
  }

  // ---- fine pass: 3 batches of 64 samples, separate R buffers ----
  MfmaW Mf;
  load_mfma_weights(lane, w2f, brf, bdf, Mf);

  const float ox = origins[ray*3+0], oy = origins[ray*3+1], oz = origins[ray*3+2];
  const float dx = dirs[ray*3+0],    dy = dirs[ray*3+1],    dz = dirs[ray*3+2];
  const float dnorm = sqrtf(dx*dx + dy*dy + dz*dz);

  RayAB ABf;
  compute_ray_ab(lane, ox, oy, oz, dx, dy, dz, sWf, ABf);

#pragma unroll
  for (int s = 0; s < 3; ++s)
    mlp_mfma_batch(lane, ABf, &sZv[wv][64*s], Mf, sHWf, sB2f, R + s*256);

  float dd[3];
#pragma unroll
  for (int s = 0; s < 3; ++s) {
    const int i = lane + 64*s;
    const float dens = fmaxf(R[s*256 + lane*4 + 3], 0.f);
    const float zcv = sZv[wv][i];
    const float znv = (i < NZ-1) ? sZv[wv][i+1] : 0.f;
    const float td = (i == NZ-1) ? 1e10f : fmaxf(znv - zcv, 0.f);
    dd[s] = fminf(dens * (td * dnorm), 1e4f);
  }

  float excl[3];
  float offset = 0.f;
#pragma unroll
  for (int s = 0; s < 3; ++s) {
    const float incl = wave_incl_scan(dd[s], lane);
    excl[s] = offset + incl - dd[s];
    offset += __shfl(incl, 63);
  }

  float aw = 0.f, awz = 0.f, ac0 = 0.f, ac1 = 0.f, ac2 = 0.f, awz0 = 0.f;
#pragma unroll
  for (int s = 0; s < 3; ++s) {
    const int i = lane + 64*s;
    const float4 rr = *(const float4*)(&R[s*256 + lane*4]);
    const float wgt = (1.f - expf(-dd[s])) * expf(-excl[s]);
    aw   += wgt;
    awz  += wgt * sZv[wv][i];
    ac0  += wgt * sigmoidf(rr.x);
    ac1  += wgt * sigmoidf(rr.y);
    ac2  += wgt * sigmoidf(rr.z);
    awz0 += wgt * sZv0[i];
  }
  aw  = wave_sum(aw);  awz = wave_sum(awz); ac0 = wave_sum(ac0);
  ac1 = wave_sum(ac1); ac2 = wave_sum(ac2); awz0 = wave_sum(awz0);

  if (lane == 0) {
    const float bk0 = bkgd[0], bk1 = bkgd[1], bk2 = bkgd[2];
    const float o0x = origins[0], o0y = origins[1], o0z = origins[2];
    const float d0x = dirs[0],    d0y = dirs[1],    d0z = dirs[2];
    const float oma = 1.f - aw;
    float* o = out + (size_t)ray * 16 + 8;
    o[0] = ac0 + bk0 * oma;
    o[1] = ac1 + bk1 * oma;
    o[2] = ac2 + bk2 * oma;
    o[3] = awz;
    o[4] = aw;
    o[5] = aw * o0x + awz0 * d0x;
    o[6] = aw * o0y + awz0 * d0y;
    o[7] = aw * o0z + awz0 * d0z;
  }
}

extern "C" void kernel_launch(void* const* d_in, const int* in_sizes, int n_in,
                              void* d_out, int out_size, void* d_ws, size_t ws_size,
                              hipStream_t stream) {
  const float* origins = (const float*)d_in[0];
  const float* dirs    = (const float*)d_in[1];
  const float* nearp   = (const float*)d_in[2];
  const float* farp    = (const float*)d_in[3];
  const float* bkgd    = (const float*)d_in[4];
  const float* w1c  = (const float*)d_in[5];
  const float* b1c  = (const float*)d_in[6];
  const float* w2c  = (const float*)d_in[7];
  const float* b2c  = (const float*)d_in[8];
  const float* wrc  = (const float*)d_in[9];
  const float* brc  = (const float*)d_in[10];
  const float* wdc  = (const float*)d_in[11];
  const float* bdc  = (const float*)d_in[12];
  const float* w1f  = (const float*)d_in[13];
  const float* b1f  = (const float*)d_in[14];
  const float* w2f  = (const float*)d_in[15];
  const float* b2f_ = (const float*)d_in[16];
  const float* wrf  = (const float*)d_in[17];
  const float* brf  = (const float*)d_in[18];
  const float* wdf  = (const float*)d_in[19];
  const float* bdf  = (const float*)d_in[20];

  float* gz0 = (float*)d_ws;   // 192 floats = 768 B of scratch

  nerf_z0_kernel<<<1, 64, 0, stream>>>(
      origins, dirs, nearp, farp,
      w1c, b1c, w2c, b2c, wrc, brc, wdc, bdc, gz0);

  nerf_fused_kernel<<<NRAYS/4, 256, 0, stream>>>(
      origins, dirs, nearp, farp, bkgd,
      w1c, b1c, w2c, b2c, wrc, brc, wdc, bdc,
      w1f, b1f, w2f, b2f_, wrf, brf, wdf, bdf,
      gz0, (float*)d_out);
}

// Round 15
// 442.503 us; speedup vs baseline: 1.5201x; 1.5201x over previous
//
#include <hip/hip_runtime.h>
#include <math.h>

#define NRAYS 16384
#define NC    64
#define NF    128
#define NZ    192   // NC + NF
#define H     64

typedef __attribute__((ext_vector_type(8))) short bf16x8;  // 8 bf16 (4 VGPRs)
typedef __attribute__((ext_vector_type(4))) float f32x4;   // MFMA C/D
typedef __attribute__((ext_vector_type(4))) int   i32x4;

__device__ __forceinline__ float wave_incl_scan(float v, int lane) {
#pragma unroll
  for (int off = 1; off < 64; off <<= 1) {
    float n = __shfl_up(v, off);
    v = (lane >= off) ? v + n : v;
  }
  return v;
}

__device__ __forceinline__ float wave_incl_max_scan(float v, int lane) {
#pragma unroll
  for (int off = 1; off < 64; off <<= 1) {
    float n = __shfl_up(v, off);
    v = (lane >= off) ? fmaxf(v, n) : v;
  }
  return v;
}

__device__ __forceinline__ float wave_sum(float v) {
#pragma unroll
  for (int off = 32; off > 0; off >>= 1) v += __shfl_xor(v, off);
  return v;
}

// fp32 -> bf16 hi + bf16 lo (truncation split; 3-term MFMA has rel err ~2^-15).
__device__ __forceinline__ void split_bf16(float f, short& hi, short& lo) {
  unsigned u = __float_as_uint(f);
  hi = (short)(u >> 16);
  float rem = f - __uint_as_float(u & 0xFFFF0000u);   // exact
  lo = (short)(__float_as_uint(rem) >> 16);
}

__device__ __forceinline__ float sigmoidf(float x) {
  return 1.f / (1.f + expf(-x));
}

// Layer-1 weights in LDS — read 16x per ray (a/b precompute).
struct __align__(16) WLds {
  float W1b[H][4];   // {w1[0][k], w1[1][k], w1[2][k], b1[k]}
};

// h1_k = relu(a_k + z*b_k); a,b per-ray constants in registers (R11 win).
struct RayAB { float a[16]; float b[16]; };   // idx = kt*8 + j

__device__ __forceinline__ void compute_ray_ab(
    int lane, float ox, float oy, float oz, float dx, float dy, float dz,
    const WLds& W, RayAB& AB)
{
  const int quad = lane >> 4;
#pragma unroll
  for (int kt = 0; kt < 2; ++kt) {
#pragma unroll
    for (int j = 0; j < 8; ++j) {
      const int k = kt*32 + quad*8 + j;
      const float4 wv = *(const float4*)(&W.W1b[k][0]);
      AB.a[kt*8+j] = fmaf(ox, wv.x, fmaf(oy, wv.y, fmaf(oz, wv.z, wv.w)));
      AB.b[kt*8+j] = fmaf(dx, wv.x, fmaf(dy, wv.y, dz * wv.z));
    }
  }
}

// Register-resident w2 fragments (3-term split, R12 numerics).
// 16x16x32 bf16 layouts (HW-verified, guide §3).
struct MfmaW {
  bf16x8 Bhi[2][4], Blo[2][4];  // w2 [kt][jt]
  float  hbown;                 // head bias for this lane's c = n16&3
};

__device__ __forceinline__ void load_mfma_weights(
    int lane,
    const float* __restrict__ w2,
    const float* __restrict__ br, const float* __restrict__ bd,
    MfmaW& M)
{
  const int quad = lane >> 4, n16 = lane & 15;
#pragma unroll
  for (int kt = 0; kt < 2; ++kt) {
#pragma unroll
    for (int jt = 0; jt < 4; ++jt) {
#pragma unroll
      for (int j = 0; j < 8; ++j) {
        const int k = kt*32 + quad*8 + j;
        short hi, lo;
        split_bf16(w2[k*H + jt*16 + n16], hi, lo);
        M.Bhi[kt][jt][j] = hi; M.Blo[kt][jt][j] = lo;
      }
    }
  }
  const int c = n16 & 3;
  M.hbown = (c == 0) ? br[0] : (c == 1) ? br[1] : (c == 2) ? br[2] : bd[0];
}

// One 64-sample MLP batch. Layer1: regs. Layer2: 3-term split-bf16 MFMA.
// Head: in-lane fp32 (LDS weights) + halving butterfly with stage 1 fused
// (correctness-proven in R14). Output R[sample*4 + c], bias included.
__device__ __forceinline__ void mlp_mfma_batch(
    int lane, const RayAB& AB,
    const float* __restrict__ zsrc, const MfmaW& M,
    const float (*__restrict__ sHW)[4], const float* __restrict__ sB2,
    float* __restrict__ R)
{
  const int quad = lane >> 4, n16 = lane & 15;
  float b2q[4];
#pragma unroll
  for (int jt = 0; jt < 4; ++jt) b2q[jt] = sB2[jt*16 + n16];
#pragma unroll 1   // rolled: prevents register blow-up (R5/R6 lesson)
  for (int mt = 0; mt < 4; ++mt) {
    const float z = zsrc[mt*16 + n16];
    f32x4 C[4];
#pragma unroll
    for (int jt = 0; jt < 4; ++jt)
      C[jt] = (f32x4){b2q[jt], b2q[jt], b2q[jt], b2q[jt]};
#pragma unroll
    for (int kt = 0; kt < 2; ++kt) {
      // h1 with truncation hi/lo split (pair-packed, 3 int ops per word)
      i32x4 hip, lop;
#pragma unroll
      for (int j2 = 0; j2 < 4; ++j2) {
        const float h0 = fmaxf(fmaf(z, AB.b[kt*8+2*j2],   AB.a[kt*8+2*j2]),   0.f);
        const float h1 = fmaxf(fmaf(z, AB.b[kt*8+2*j2+1], AB.a[kt*8+2*j2+1]), 0.f);
        const unsigned u0 = __float_as_uint(h0), u1 = __float_as_uint(h1);
        hip[j2] = (int)((u0 >> 16) | (u1 & 0xFFFF0000u));
        const float r0 = h0 - __uint_as_float(u0 & 0xFFFF0000u);
        const float r1 = h1 - __uint_as_float(u1 & 0xFFFF0000u);
        lop[j2] = (int)((__float_as_uint(r0) >> 16) |
                        (__float_as_uint(r1) & 0xFFFF0000u));
      }
      union { i32x4 i; bf16x8 h; } uh, ul;
      uh.i = hip; ul.i = lop;
#pragma unroll
      for (int jt = 0; jt < 4; ++jt) {
        C[jt] = __builtin_amdgcn_mfma_f32_16x16x32_bf16(uh.h, M.Bhi[kt][jt], C[jt], 0, 0, 0);
        C[jt] = __builtin_amdgcn_mfma_f32_16x16x32_bf16(ul.h, M.Bhi[kt][jt], C[jt], 0, 0, 0);
        C[jt] = __builtin_amdgcn_mfma_f32_16x16x32_bf16(uh.h, M.Blo[kt][jt], C[jt], 0, 0, 0);
      }
    }
    // ---- head: P[r*4+c] = sum_jt relu(C[jt][r]) * sHW[jt*16+n16][c],
    // butterfly stage 1 (xor 1) fused per-r. Mapping identical to R12:
    // Q[2r]   = pair(P[4r+0], P[4r+1]),  Q[2r+1] = pair(P[4r+2], P[4r+3]).
    float4 hw[4];
#pragma unroll
    for (int jt = 0; jt < 4; ++jt)
      hw[jt] = *(const float4*)(&sHW[jt*16 + n16][0]);
    const bool b0 = (n16 & 1), b1 = (n16 & 2), b2_ = (n16 & 4), b3 = (n16 & 8);
    float Q[8];
#pragma unroll
    for (int r = 0; r < 4; ++r) {
      float p0 = 0.f, p1 = 0.f, p2 = 0.f, p3 = 0.f;
#pragma unroll
      for (int jt = 0; jt < 4; ++jt) {
        const float h2v = fmaxf(C[jt][r], 0.f);
        p0 = fmaf(h2v, hw[jt].x, p0);
        p1 = fmaf(h2v, hw[jt].y, p1);
        p2 = fmaf(h2v, hw[jt].z, p2);
        p3 = fmaf(h2v, hw[jt].w, p3);
      }
      {
        const float give = b0 ? p0 : p1;
        const float keep = b0 ? p1 : p0;
        Q[r*2 + 0] = keep + __shfl_xor(give, 1);
      }
      {
        const float give = b0 ? p2 : p3;
        const float keep = b0 ? p3 : p2;
        Q[r*2 + 1] = keep + __shfl_xor(give, 1);
      }
    }
    float U[4];
#pragma unroll
    for (int t = 0; t < 4; ++t) {
      const float give = b1 ? Q[2*t] : Q[2*t+1];
      const float keep = b1 ? Q[2*t+1] : Q[2*t];
      U[t] = keep + __shfl_xor(give, 2);
    }
    float V[2];
#pragma unroll
    for (int u = 0; u < 2; ++u) {
      const float give = b2_ ? U[2*u] : U[2*u+1];
      const float keep = b2_ ? U[2*u+1] : U[2*u];
      V[u] = keep + __shfl_xor(give, 4);
    }
    {
      const float give = b3 ? V[0] : V[1];
      const float keep = b3 ? V[1] : V[0];
      const float total = keep + __shfl_xor(give, 8);
      R[mt*64 + lane] = total + M.hbown;   // coalesced: addr = sample*4 + c
    }
  }
  __builtin_amdgcn_wave_barrier();     // R complete before readback
}

// Coarse pass for one ray, ONE wave, wave-private LDS scratch.
__device__ __forceinline__ void coarse_pass(
    int ray, int lane,
    const float* __restrict__ origins, const float* __restrict__ dirs,
    const float* __restrict__ nearp, const float* __restrict__ farp,
    const float* __restrict__ bkgd,
    const WLds& W, const MfmaW& M,
    const float (*__restrict__ sHW)[4], const float* __restrict__ sB2,
    float* __restrict__ R,
    float* __restrict__ sT, float* __restrict__ sBins,
    float* __restrict__ sCdf, float* __restrict__ sZs,
    float* __restrict__ zdst, bool emit, float* __restrict__ out)
{
  const float nearv = nearp[ray];
  const float farv  = farp[ray];
  const float ox = origins[ray*3+0], oy = origins[ray*3+1], oz = origins[ray*3+2];
  const float dx = dirs[ray*3+0],    dy = dirs[ray*3+1],    dz = dirs[ray*3+2];

  RayAB AB;
  compute_ray_ab(lane, ox, oy, oz, dx, dy, dz, W, AB);

  const float u_i  = (float)lane / 63.0f;
  const float u_n  = (float)(lane + 1) / 63.0f;
  const float tv    = nearv * (1.f - u_i) + farv * u_i;
  const float tnext = nearv * (1.f - u_n) + farv * u_n;

  sT[lane] = tv;
  if (lane < NC-1) sBins[lane] = 0.5f * (tv + tnext);
  zdst[lane] = 0.f; zdst[lane+64] = 0.f; zdst[lane+128] = 0.f;
  __builtin_amdgcn_wave_barrier();     // sT ready for the batch

  mlp_mfma_batch(lane, AB, sT, M, sHW, sB2, R);
  const float4 rr = *(const float4*)(&R[lane*4]);
  const float rgb0 = sigmoidf(rr.x), rgb1 = sigmoidf(rr.y), rgb2 = sigmoidf(rr.z);
  const float dens = fmaxf(rr.w, 0.f);

  const float dnorm = sqrtf(dx*dx + dy*dy + dz*dz);
  const float tdist = (lane == NC-1) ? 1e10f : (tnext - tv);
  const float dd    = fminf(dens * (tdist * dnorm), 1e4f);
  const float incl  = wave_incl_scan(dd, lane);
  const float excl  = incl - dd;
  const float alpha = 1.f - expf(-dd);
  const float trans = expf(-excl);
  const float w     = alpha * trans;

  if (emit) {
    const float near0 = nearp[0], far0 = farp[0];
    const float t0v   = near0 * (1.f - u_i) + far0 * u_i;
    const float s_w   = wave_sum(w);
    const float s_wt  = wave_sum(w * tv);
    const float s_c0  = wave_sum(w * rgb0);
    const float s_c1  = wave_sum(w * rgb1);
    const float s_c2  = wave_sum(w * rgb2);
    const float s_wt0 = wave_sum(w * t0v);
    if (lane == 0) {
      const float bk0 = bkgd[0], bk1 = bkgd[1], bk2 = bkgd[2];
      const float o0x = origins[0], o0y = origins[1], o0z = origins[2];
      const float d0x = dirs[0],    d0y = dirs[1],    d0z = dirs[2];
      const float oma = 1.f - s_w;
      float* o = out + (size_t)ray * 16;
      o[0] = s_c0 + bk0 * oma;
      o[1] = s_c1 + bk1 * oma;
      o[2] = s_c2 + bk2 * oma;
      o[3] = s_wt;
      o[4] = s_w;
      o[5] = s_w * o0x + s_wt0 * d0x;
      o[6] = s_w * o0y + s_wt0 * d0y;
      o[7] = s_w * o0z + s_wt0 * d0z;
    }
  }

  // ---- PDF -> CDF (62 weights = w[1..62]) ----
  const float wnext = __shfl_down(w, 1);
  const float pw = (lane < NC-2) ? wnext : 0.f;
  const float ws_sum = wave_sum(pw);
  const float pad = fmaxf(1e-5f - ws_sum, 0.f);
  const float wsp = ws_sum + pad;
  const float pdf = (lane < NC-2) ? (pw + pad * (1.f/62.f)) / wsp : 0.f;
  float ip  = wave_incl_scan(pdf, lane);
  ip = wave_incl_max_scan(ip, lane);       // exact monotone
  if (lane < 61)  sCdf[lane+1] = fminf(ip, 1.f);
  if (lane == 61) sCdf[0]  = 0.f;
  if (lane == 62) sCdf[62] = 1.f;
  __builtin_amdgcn_wave_barrier();

  // ---- inverse-CDF: 128 samples, 2 per lane ----
  const float ustep = (1.0f - 1.1920929e-07f) / 127.0f;
#pragma unroll
  for (int r = 0; r < 2; ++r) {
    const int k = lane + 64*r;
    const float u = k * ustep;
    int lo = 0, hi = 61;
    while (lo < hi) {
      const int mid = (lo + hi + 1) >> 1;
      if (sCdf[mid] <= u) lo = mid; else hi = mid - 1;
    }
    const int J = lo;
    const float cg0 = sCdf[J],  cg1 = sCdf[J+1];
    const float bg0 = sBins[J], bg1 = sBins[J+1];
    const float denom = cg1 - cg0;
    const float num   = u - cg0;
    float tt;
    if (denom > 0.f) tt = fminf(fmaxf(num / denom, 0.f), 1.f);
    else             tt = (num > 0.f) ? 1.f : 0.f;
    sZs[k] = fmaf(tt, bg1 - bg0, bg0);
  }
  __builtin_amdgcn_wave_barrier();

  // ---- stable rank merge of sorted t (64) and z (128) into zdst (192) ----
  {
    int l = 0, r = NF;
    while (l < r) { const int m = (l + r) >> 1; if (sZs[m] < tv) l = m + 1; else r = m; }
    zdst[lane + l] = tv;
  }
#pragma unroll
  for (int r2 = 0; r2 < 2; ++r2) {
    const int k = lane + 64*r2;
    const float z = sZs[k];
    int l = 0, r = NC;
    while (l < r) { const int m = (l + r) >> 1; if (sT[m] <= z) l = m + 1; else r = m; }
    zdst[k + l] = z;
  }
  __builtin_amdgcn_wave_barrier();
}

// -------- Kernel 1: ONE block, ONE wave — ray 0's merged z row -> d_ws ------
__global__ __launch_bounds__(64) void nerf_z0_kernel(
    const float* __restrict__ origins, const float* __restrict__ dirs,
    const float* __restrict__ nearp, const float* __restrict__ farp,
    const float* __restrict__ w1c, const float* __restrict__ b1c,
    const float* __restrict__ w2c, const float* __restrict__ b2c,
    const float* __restrict__ wrc, const float* __restrict__ brc,
    const float* __restrict__ wdc, const float* __restrict__ bdc,
    float* __restrict__ gz0)
{
  __shared__ WLds sW;
  __shared__ float sHW[H][4];
  __shared__ float sB2[H];
  __shared__ float sT[NC], sBins[NC], sCdf[NC], sZs[NF], sZv0[NZ];
  __shared__ float sR[256];

  const int lane = threadIdx.x;
  {
    const int k = lane;
    sW.W1b[k][0] = w1c[0*H + k];
    sW.W1b[k][1] = w1c[1*H + k];
    sW.W1b[k][2] = w1c[2*H + k];
    sW.W1b[k][3] = b1c[k];
    sHW[k][0] = wrc[k*3 + 0];
    sHW[k][1] = wrc[k*3 + 1];
    sHW[k][2] = wrc[k*3 + 2];
    sHW[k][3] = wdc[k];
    sB2[k]    = b2c[k];
  }
  __syncthreads();

  MfmaW Mc;
  load_mfma_weights(lane, w2c, brc, bdc, Mc);

  coarse_pass(0, lane, origins, dirs, nearp, farp, /*bkgd*/nullptr,
              sW, Mc, sHW, sB2, sR, sT, sBins, sCdf, sZs, sZv0,
              /*emit=*/false, /*out=*/nullptr);

#pragma unroll
  for (int s = 0; s < 3; ++s) gz0[lane + 64*s] = sZv0[lane + 64*s];
}

// -------- Kernel 2: 4 waves = 4 rays per block; z0 row read from d_ws -------
// NO launch_bounds waves-cap: R14's (256,4) made the allocator spill
// wholesale (VGPR 64, 720MB scratch writes). Let it land naturally (~R12).
__global__ __launch_bounds__(256) void nerf_fused_kernel(
    const float* __restrict__ origins, const float* __restrict__ dirs,
    const float* __restrict__ nearp, const float* __restrict__ farp,
    const float* __restrict__ bkgd,
    const float* __restrict__ w1c, const float* __restrict__ b1c,
    const float* __restrict__ w2c, const float* __restrict__ b2c,
    const float* __restrict__ wrc, const float* __restrict__ brc,
    const float* __restrict__ wdc, const float* __restrict__ bdc,
    const float* __restrict__ w1f, const float* __restrict__ b1f,
    const float* __restrict__ w2f, const float* __restrict__ b2f_,
    const float* __restrict__ wrf, const float* __restrict__ brf,
    const float* __restrict__ wdf, const float* __restrict__ bdf,
    const float* __restrict__ gz0, float* __restrict__ out)
{
  __shared__ WLds sWc, sWf;
  __shared__ float sHWc[H][4], sHWf[H][4];
  __shared__ float sB2c[H], sB2f[H];
  __shared__ float sT[4][NC];
  __shared__ float sBins[4][NC];
  __shared__ float sCdf[4][NC];
  __shared__ float sZs[4][NF];
  __shared__ float sZv[4][NZ];
  __shared__ float sZv0[NZ];                // ray 0's fine z row (quirk)
  __shared__ float sR[4][3*256];            // per-wave logits, 3 fine buffers

  const int tid  = threadIdx.x;
  const int wv   = tid >> 6;
  const int lane = tid & 63;
  const int ray  = blockIdx.x * 4 + wv;

  if (tid < 64) {
    const int k = tid;
    sWc.W1b[k][0] = w1c[0*H + k];
    sWc.W1b[k][1] = w1c[1*H + k];
    sWc.W1b[k][2] = w1c[2*H + k];
    sWc.W1b[k][3] = b1c[k];
    sHWc[k][0] = wrc[k*3+0]; sHWc[k][1] = wrc[k*3+1];
    sHWc[k][2] = wrc[k*3+2]; sHWc[k][3] = wdc[k];
    sB2c[k] = b2c[k];
  } else if (tid < 128) {
    const int k = tid - 64;
    sWf.W1b[k][0] = w1f[0*H + k];
    sWf.W1b[k][1] = w1f[1*H + k];
    sWf.W1b[k][2] = w1f[2*H + k];
    sWf.W1b[k][3] = b1f[k];
    sHWf[k][0] = wrf[k*3+0]; sHWf[k][1] = wrf[k*3+1];
    sHWf[k][2] = wrf[k*3+2]; sHWf[k][3] = wdf[k];
    sB2f[k] = b2f_[k];
  }
  if (tid < NZ) sZv0[tid] = gz0[tid];       // z0 row from kernel 1
  __syncthreads();

  float* R = sR[wv];

  // ---- coarse pass (own ray only — no per-block ray-0 recompute) ----
  {
    MfmaW Mc;
    load_mfma_weights(lane, w2c, brc, bdc, Mc);
    coarse_pass(ray, lane, origins, dirs, nearp, farp, bkgd,
                sWc, Mc, sHWc, sB2c, R,
                sT[wv], sBins[wv], sCdf[wv], sZs[wv], sZv[wv], true, out);
  }

  // ---- fine pass: 3 batches of 64 samples, separate R buffers ----
  MfmaW Mf;
  load_mfma_weights(lane, w2f, brf, bdf, Mf);

  const float ox = origins[ray*3+0], oy = origins[ray*3+1], oz = origins[ray*3+2];
  const float dx = dirs[ray*3+0],    dy = dirs[ray*3+1],    dz = dirs[ray*3+2];
  const float dnorm = sqrtf(dx*dx + dy*dy + dz*dz);

  RayAB ABf;
  compute_ray_ab(lane, ox, oy, oz, dx, dy, dz, sWf, ABf);

#pragma unroll
  for (int s = 0; s < 3; ++s)
    mlp_mfma_batch(lane, ABf, &sZv[wv][64*s], Mf, sHWf, sB2f, R + s*256);

  float dd[3];
#pragma unroll
  for (int s = 0; s < 3; ++s) {
    const int i = lane + 64*s;
    const float dens = fmaxf(R[s*256 + lane*4 + 3], 0.f);
    const float zcv = sZv[wv][i];
    const float znv = (i < NZ-1) ? sZv[wv][i+1] : 0.f;
    const float td = (i == NZ-1) ? 1e10f : fmaxf(znv - zcv, 0.f);
    dd[s] = fminf(dens * (td * dnorm), 1e4f);
  }

  float excl[3];
  float offset = 0.f;
#pragma unroll
  for (int s = 0; s < 3; ++s) {
    const float incl = wave_incl_scan(dd[s], lane);
    excl[s] = offset + incl - dd[s];
    offset += __shfl(incl, 63);
  }

  float aw = 0.f, awz = 0.f, ac0 = 0.f, ac1 = 0.f, ac2 = 0.f, awz0 = 0.f;
#pragma unroll
  for (int s = 0; s < 3; ++s) {
    const int i = lane + 64*s;
    const float4 rr = *(const float4*)(&R[s*256 + lane*4]);
    const float wgt = (1.f - expf(-dd[s])) * expf(-excl[s]);
    aw   += wgt;
    awz  += wgt * sZv[wv][i];
    ac0  += wgt * sigmoidf(rr.x);
    ac1  += wgt * sigmoidf(rr.y);
    ac2  += wgt * sigmoidf(rr.z);
    awz0 += wgt * sZv0[i];
  }
  aw  = wave_sum(aw);  awz = wave_sum(awz); ac0 = wave_sum(ac0);
  ac1 = wave_sum(ac1); ac2 = wave_sum(ac2); awz0 = wave_sum(awz0);

  if (lane == 0) {
    const float bk0 = bkgd[0], bk1 = bkgd[1], bk2 = bkgd[2];
    const float o0x = origins[0], o0y = origins[1], o0z = origins[2];
    const float d0x = dirs[0],    d0y = dirs[1],    d0z = dirs[2];
    const float oma = 1.f - aw;
    float* o = out + (size_t)ray * 16 + 8;
    o[0] = ac0 + bk0 * oma;
    o[1] = ac1 + bk1 * oma;
    o[2] = ac2 + bk2 * oma;
    o[3] = awz;
    o[4] = aw;
    o[5] = aw * o0x + awz0 * d0x;
    o[6] = aw * o0y + awz0 * d0y;
    o[7] = aw * o0z + awz0 * d0z;
  }
}

extern "C" void kernel_launch(void* const* d_in, const int* in_sizes, int n_in,
                              void* d_out, int out_size, void* d_ws, size_t ws_size,
                              hipStream_t stream) {
  const float* origins = (const float*)d_in[0];
  const float* dirs    = (const float*)d_in[1];
  const float* nearp   = (const float*)d_in[2];
  const float* farp    = (const float*)d_in[3];
  const float* bkgd    = (const float*)d_in[4];
  const float* w1c  = (const float*)d_in[5];
  const float* b1c  = (const float*)d_in[6];
  const float* w2c  = (const float*)d_in[7];
  const float* b2c  = (const float*)d_in[8];
  const float* wrc  = (const float*)d_in[9];
  const float* brc  = (const float*)d_in[10];
  const float* wdc  = (const float*)d_in[11];
  const float* bdc  = (const float*)d_in[12];
  const float* w1f  = (const float*)d_in[13];
  const float* b1f  = (const float*)d_in[14];
  const float* w2f  = (const float*)d_in[15];
  const float* b2f_ = (const float*)d_in[16];
  const float* wrf  = (const float*)d_in[17];
  const float* brf  = (const float*)d_in[18];
  const float* wdf  = (const float*)d_in[19];
  const float* bdf  = (const float*)d_in[20];

  float* gz0 = (float*)d_ws;   // 192 floats = 768 B of scratch

  nerf_z0_kernel<<<1, 64, 0, stream>>>(
      origins, dirs, nearp, farp,
      w1c, b1c, w2c, b2c, wrc, brc, wdc, bdc, gz0);

  nerf_fused_kernel<<<NRAYS/4, 256, 0, stream>>>(
      origins, dirs, nearp, farp, bkgd,
      w1c, b1c, w2c, b2c, wrc, brc, wdc, bdc,
      w1f, b1f, w2f, b2f_, wrf, brf, wdf, bdf,
      gz0, (float*)d_out);
}